// Round 8
// baseline (74.440 us; speedup 1.0000x reference)
//
#include <hip/hip_runtime.h>
#include <hip/hip_bf16.h>
#include <math.h>

// Problem constants
#define NB 8
#define LN 4096       // sequence length L
#define NH 8
#define NE 64
#define NC 512        // NH*NE channels
#define NM 64         // modes kept
#define LMASK 4095

typedef short s16x8 __attribute__((ext_vector_type(8)));
typedef float f32x4 __attribute__((ext_vector_type(4)));

// ws layout (in floats):
//  egf : bf16[128kc][8mt][64][8]        @ 0        (1 MB)  fwd twiddle A-fragments
//  tf  : bf16[4kk][256lt][64][8]        @ 262144   (1 MB)  inv twiddle B-fragments
//  gf  : bf16[8b][4kk][32ct][64][8]     @ 524288   (1 MB)  mixed-spectrum A-fragments
//  xp  : f32[8ks][8b][8h][64i][128m±]   @ 786432   (16 MB) partial fwd GEMM outputs
//  xs  : f32[8b][8h][64i][128m±]        @ 4980736  (2 MB)  ks-summed spectrum
#define WS_EGF 0
#define WS_TF  262144
#define WS_GF  524288
#define WS_XP  786432
#define WS_XS  4980736

static __device__ __forceinline__ unsigned short bf16bits(float f) {
    __hip_bfloat16 b = __float2bfloat16(f);
    return *reinterpret_cast<unsigned short*>(&b);
}

// Both twiddle tables in one launch. Blocks 0..255: egf (fwd A-frags);
// blocks 256..511: tf (inv B-frags).
__global__ __launch_bounds__(256) void k_tables(unsigned short* __restrict__ egf,
                                                unsigned short* __restrict__ tfp) {
    const int bid = blockIdx.x;
    const int s = (bid & 255) * 256 + threadIdx.x;   // 0..65535
    const int lane = s & 63;
    unsigned short v[8];
    if (bid < 256) {
        // E[2m][l]=cos, E[2m+1][l]=-sin ; slot s=(kc<<9)|(mt<<6)|lane
        int mt = (s >> 6) & 7, kc = s >> 9;
        int r = lane & 15, kg = lane >> 4;
        int mpm = mt * 16 + r;
        int m = mpm >> 1, isim = mpm & 1;
        #pragma unroll
        for (int j = 0; j < 8; ++j) {
            int l = kc * 32 + kg * 8 + j;
            int tw = (m * l) & LMASK;
            float ang = (6.283185307179586f / 4096.0f) * (float)tw;
            v[j] = bf16bits(isim ? -sinf(ang) : cosf(ang));
        }
    } else {
        // T[l][2m]=cos, T[l][2m+1]=sin ; slot s=(kk<<14)|(lt<<6)|lane
        int lt = (s >> 6) & 255, kk = s >> 14;
        int l = lt * 16 + (lane & 15);
        int khi = (lane >> 4) * 8;
        #pragma unroll
        for (int j = 0; j < 8; ++j) {
            int mp = kk * 32 + khi + j;
            int m = mp >> 1;
            int tw = (m * l) & LMASK;
            float ang = (6.283185307179586f / 4096.0f) * (float)tw;
            v[j] = bf16bits((mp & 1) ? sinf(ang) : cosf(ang));
        }
    }
    uint4 pk;
    pk.x = (unsigned)v[0] | ((unsigned)v[1] << 16);
    pk.y = (unsigned)v[2] | ((unsigned)v[3] << 16);
    pk.z = (unsigned)v[4] | ((unsigned)v[5] << 16);
    pk.w = (unsigned)v[6] | ((unsigned)v[7] << 16);
    unsigned short* dst = (bid < 256) ? egf : tfp;
    *reinterpret_cast<uint4*>(dst + (size_t)s * 8) = pk;
}

// Fused stage 1 (v4 = proven v1 LDS-transpose + dbuf + 64-l tiles, 1 barrier/tile).
// grid (8 ks, 8 h, 8 b) = 512 blocks, block 256 = 4 waves, 2 blocks/CU.
// Per block: K-chunk 512 l = 8 tiles x 64 l. LDS: 2 buffers of [4 st][64 l][16 i] bf16.
// Staging: thread loads rows sl & sl+32 (8 i each, float4 x2), packs bf16, 2 uint4 LDS writes.
// Compute: wave w owns i-subtile w; per tile: 2 kk x { 8 egf A-frags (L2), B-frag gather
// (8 ds_read_u16), 8 MFMA }. kc order = ks*16 + 2t + kk = sequential -> bit-identical to v1.
__global__ __launch_bounds__(256, 2) void k_fs1(const float* __restrict__ q,
                                                const unsigned short* __restrict__ egf,
                                                float* __restrict__ xp) {
    __shared__ unsigned short tile[2][4096];   // 2 x 8 KB
    const int ks = blockIdx.x, h = blockIdx.y, b = blockIdx.z;
    const int tid = threadIdx.x;
    const int w = tid >> 6, lane = tid & 63;

    // staging assignment
    const int sl = tid >> 3;            // 0..31 (also handles sl+32)
    const int sc = tid & 7;             // i-chunk (8 i)
    const float* qbase = q + (((size_t)b * LN + (size_t)ks * 512) * NH + h) * NE + sc * 8;
    const int wslot0 = (sc >> 1) * 128 + sl * 2 + (sc & 1);          // uint4 units
    const int wslot1 = (sc >> 1) * 128 + (sl + 32) * 2 + (sc & 1);

    // B-fragment gather base (per wave subtile), element units
    const unsigned short* tbase0 = &tile[0][0] + w * 1024 + (lane >> 4) * 128 + (lane & 15);
    const unsigned short* tbase1 = &tile[1][0] + w * 1024 + (lane >> 4) * 128 + (lane & 15);

    f32x4 acc[8];
    #pragma unroll
    for (int mt = 0; mt < 8; ++mt) acc[mt] = (f32x4)(0.0f);

    float4 ra0, ra1, rb0, rb1;   // current tile's staged rows
    float4 na0, na1, nb0, nb1;   // next tile's rows

#define FS1_GLOAD(T, A0, A1, B0, B1)                                              \
    {                                                                             \
        const float* p0_ = qbase + ((size_t)(T) * 64 + sl) * NC;                  \
        const float* p1_ = qbase + ((size_t)(T) * 64 + sl + 32) * NC;             \
        A0 = *reinterpret_cast<const float4*>(p0_);                               \
        A1 = *reinterpret_cast<const float4*>(p0_ + 4);                           \
        B0 = *reinterpret_cast<const float4*>(p1_);                               \
        B1 = *reinterpret_cast<const float4*>(p1_ + 4);                           \
    }

#define FS1_PACK(A0, A1, PK)                                                      \
    {                                                                             \
        PK.x = (unsigned)bf16bits(A0.x) | ((unsigned)bf16bits(A0.y) << 16);       \
        PK.y = (unsigned)bf16bits(A0.z) | ((unsigned)bf16bits(A0.w) << 16);       \
        PK.z = (unsigned)bf16bits(A1.x) | ((unsigned)bf16bits(A1.y) << 16);       \
        PK.w = (unsigned)bf16bits(A1.z) | ((unsigned)bf16bits(A1.w) << 16);       \
    }

    FS1_GLOAD(0, ra0, ra1, rb0, rb1)

    for (int t = 0; t < 8; ++t) {
        const int cur = t & 1;
        uint4* tq4 = reinterpret_cast<uint4*>(&tile[cur][0]);
        uint4 pk0, pk1;
        FS1_PACK(ra0, ra1, pk0)
        FS1_PACK(rb0, rb1, pk1)
        tq4[wslot0] = pk0;
        tq4[wslot1] = pk1;
        if (t < 7) FS1_GLOAD(t + 1, na0, na1, nb0, nb1)
        __syncthreads();

        const unsigned short* tb = cur ? tbase1 : tbase0;
        #pragma unroll
        for (int kk = 0; kk < 2; ++kk) {
            const int kc = ks * 16 + t * 2 + kk;
            const unsigned short* ep = egf + (((size_t)kc * 8) * 64 + lane) * 8;
            s16x8 af[8];
            #pragma unroll
            for (int mt = 0; mt < 8; ++mt)
                af[mt] = *reinterpret_cast<const s16x8*>(ep + (size_t)mt * 512);
            s16x8 bfr;
            const unsigned short* tp = tb + kk * 512;
            #pragma unroll
            for (int j = 0; j < 8; ++j) bfr[j] = (short)tp[j * 16];
            #pragma unroll
            for (int mt = 0; mt < 8; ++mt)
                acc[mt] = __builtin_amdgcn_mfma_f32_16x16x32_bf16(af[mt], bfr, acc[mt], 0, 0, 0);
        }
        ra0 = na0; ra1 = na1; rb0 = nb0; rb1 = nb1;
    }
#undef FS1_PACK
#undef FS1_GLOAD

    // Epilogue: D row = m±-local = (lane>>4)*4 + reg, col = i-local = lane&15.
    const int i = w * 16 + (lane & 15);
    float* xpb = xp + ((size_t)ks * 64 + b * 8 + h) * (64 * 128) + (size_t)i * 128 + (lane >> 4) * 4;
    #pragma unroll
    for (int mt = 0; mt < 8; ++mt)
        *reinterpret_cast<f32x4*>(xpb + mt * 16) = acc[mt];
}

// Sum the 8 K-split partials (float4-vectorized; same per-element order).
__global__ __launch_bounds__(256) void k_presum(const float* __restrict__ xp,
                                                float* __restrict__ xs) {
    int e4 = blockIdx.x * 256 + threadIdx.x;     // 0..131071 float4s
    const f32x4* xp4 = reinterpret_cast<const f32x4*>(xp);
    f32x4 s = (f32x4)(0.0f);
    #pragma unroll
    for (int ks = 0; ks < 8; ++ks) s += xp4[(size_t)ks * 131072 + e4];
    reinterpret_cast<f32x4*>(xs)[e4] = s;
}

// Stage 2 (v3, proven): channel mix, gf written directly. grid 256 blocks
// (XCD-swizzled), block 256. sid -> x = sid&7, idx = sid>>3; r = x*8 + (idx&7)
// -> og = r>>3, h = r&7; bb = idx>>3 -> b in {bb*2, bb*2+1}. The 4 bb-partner
// blocks share the same w1/w2 slice on one XCD -> w read once from HBM.
// Block stages xs[2b][h][64i][64m] (64 KB) to LDS, then o-loop runs from LDS.
__global__ __launch_bounds__(256) void k_s2(const float* __restrict__ w1,
                                            const float* __restrict__ w2,
                                            const float* __restrict__ xs,
                                            unsigned short* __restrict__ gf) {
    __shared__ float2 sxs[2][64][64];    // [bsub][i][m] = 64 KB
    const int sid = blockIdx.x;
    const int x   = sid & 7;
    const int idx = sid >> 3;
    const int r   = x * 8 + (idx & 7);   // (og,h) index
    const int og  = r >> 3, h = r & 7;
    const int bb  = idx >> 3;            // 0..3
    const int tt  = threadIdx.x;

    {
        float4* dst = reinterpret_cast<float4*>(&sxs[0][0][0]);
        #pragma unroll
        for (int bs = 0; bs < 2; ++bs) {
            const float4* s4 = reinterpret_cast<const float4*>(
                xs + ((size_t)((bb * 2 + bs) * 8 + h)) * 8192);
            #pragma unroll
            for (int k = 0; k < 8; ++k)
                dst[bs * 2048 + k * 256 + tt] = s4[k * 256 + tt];
        }
    }
    __syncthreads();

    const int m    = tt & 63;
    const int osub = tt >> 6;            // 0..3
    const int o0   = og * 8 + osub * 2;  // 2 o per thread

    float re[2][2], im[2][2];            // [oo][bs]
    #pragma unroll
    for (int oo = 0; oo < 2; ++oo)
        #pragma unroll
        for (int bs = 0; bs < 2; ++bs) { re[oo][bs] = 0.f; im[oo][bs] = 0.f; }

    const float* w1p = w1 + (size_t)h * (NE * NE * NM) + (size_t)o0 * NM + m;
    const float* w2p = w2 + (size_t)h * (NE * NE * NM) + (size_t)o0 * NM + m;

    #pragma unroll 2
    for (int i = 0; i < NE; ++i) {
        float wr0 = w1p[(size_t)i * (NE * NM)];
        float wi0 = w2p[(size_t)i * (NE * NM)];
        float wr1 = w1p[(size_t)i * (NE * NM) + NM];
        float wi1 = w2p[(size_t)i * (NE * NM) + NM];
        #pragma unroll
        for (int bs = 0; bs < 2; ++bs) {
            float2 xv = sxs[bs][i][m];
            re[0][bs] = fmaf(xv.x, wr0, fmaf(-xv.y, wi0, re[0][bs]));
            im[0][bs] = fmaf(xv.x, wi0, fmaf( xv.y, wr0, im[0][bs]));
            re[1][bs] = fmaf(xv.x, wr1, fmaf(-xv.y, wi1, re[1][bs]));
            im[1][bs] = fmaf(xv.x, wi1, fmaf( xv.y, wr1, im[1][bs]));
        }
    }

    const float sca = (m == 0 ? 1.0f : 2.0f) / (float)LN;  // (2-delta_m0)/L fold
    // G[2m][c]=s*re, G[2m+1][c]=-s*im into A-fragment layout:
    // slot = ((b*4 + (m>>4))*32 + (c>>4))*64 + ((m&15)>>2)*16 + (c&15), elems ((m&3)<<1)+{0,1}
    const int kk  = m >> 4;
    const int khi = ((m & 15) >> 2) * 16;
    const int jj  = (m & 3) << 1;
    #pragma unroll
    for (int oo = 0; oo < 2; ++oo) {
        const int c = h * 64 + o0 + oo;
        #pragma unroll
        for (int bs = 0; bs < 2; ++bs) {
            const int b = bb * 2 + bs;
            size_t slot = (((size_t)b * 4 + kk) * 32 + (c >> 4)) * 64 + khi + (c & 15);
            unsigned int pk = (unsigned)bf16bits(re[oo][bs] * sca) |
                              ((unsigned)bf16bits(-im[oo][bs] * sca) << 16);
            *reinterpret_cast<unsigned int*>(gf + slot * 8 + jj) = pk;
        }
    }
}

// Stage 3 MFMA: per b: out[l][c] = sum_mp T[l][mp] * G[mp][c].  M=c(128/block), N=l(64/block), K=128.
// grid (64 lb, 4 cb, 8 b), block 256 = 4 waves; wave w owns c-quarter [w*32, w*32+32).
// Zero LDS / zero barriers; both operand tables stream from L2.
__global__ __launch_bounds__(256, 2) void k_s3(const unsigned short* __restrict__ gf,
                                               const unsigned short* __restrict__ tfp,
                                               float* __restrict__ out) {
    const int lb = blockIdx.x;   // l base = lb*64
    const int cb = blockIdx.y;   // c base = cb*128
    const int b  = blockIdx.z;
    const int tid = threadIdx.x;
    const int w = tid >> 6, lane = tid & 63;

    const unsigned short* ga = gf + ((((size_t)b * 4) * 32 + cb * 8 + w * 2) * 64 + lane) * 8;
    const unsigned short* tb = tfp + (((size_t)lb * 4) * 64 + lane) * 8;

    f32x4 acc[2][4] = {};
    s16x8 af[3][2], bf[3][4];

#define S3_LOAD(T, SLOT)                                                          \
    {                                                                             \
        const unsigned short* gp_ = ga + (size_t)(T) * (32 * 64 * 8);             \
        const unsigned short* tp_ = tb + (size_t)(T) * (256 * 64 * 8);            \
        af[SLOT][0] = *reinterpret_cast<const s16x8*>(gp_);                       \
        af[SLOT][1] = *reinterpret_cast<const s16x8*>(gp_ + 64 * 8);              \
        bf[SLOT][0] = *reinterpret_cast<const s16x8*>(tp_);                       \
        bf[SLOT][1] = *reinterpret_cast<const s16x8*>(tp_ + 64 * 8);              \
        bf[SLOT][2] = *reinterpret_cast<const s16x8*>(tp_ + 2 * 64 * 8);          \
        bf[SLOT][3] = *reinterpret_cast<const s16x8*>(tp_ + 3 * 64 * 8);          \
    }

    S3_LOAD(0, 0)
    S3_LOAD(1, 1)

    #pragma unroll
    for (int t = 0; t < 4; ++t) {
        const int slot = t % 3;
        if (t + 2 < 4) { const int ns = (t + 2) % 3; S3_LOAD(t + 2, ns) }
        #pragma unroll
        for (int mi = 0; mi < 2; ++mi)
            #pragma unroll
            for (int ni = 0; ni < 4; ++ni)
                acc[mi][ni] = __builtin_amdgcn_mfma_f32_16x16x32_bf16(
                    af[slot][mi], bf[slot][ni], acc[mi][ni], 0, 0, 0);
    }
#undef S3_LOAD

    // D[row=c_local][col=l_local]; f32x4 regs span 4 consecutive c.
    const int c0 = cb * 128 + w * 32 + (lane >> 4) * 4;
    const int l0 = lb * 64 + (lane & 15);
    #pragma unroll
    for (int mi = 0; mi < 2; ++mi)
        #pragma unroll
        for (int ni = 0; ni < 4; ++ni) {
            float* op = out + ((size_t)b * LN + l0 + ni * 16) * NC + c0 + mi * 16;
            *reinterpret_cast<f32x4*>(op) = acc[mi][ni];
        }
}

extern "C" void kernel_launch(void* const* d_in, const int* in_sizes, int n_in,
                              void* d_out, int out_size, void* d_ws, size_t ws_size,
                              hipStream_t stream) {
    const float* q  = (const float*)d_in[0];
    // d_in[1] (k) and d_in[2] (v) are unused by the reference
    const float* w1 = (const float*)d_in[3];
    const float* w2 = (const float*)d_in[4];
    float* out = (float*)d_out;
    float* ws  = (float*)d_ws;

    unsigned short* egf = (unsigned short*)(ws + WS_EGF);
    unsigned short* tfp = (unsigned short*)(ws + WS_TF);
    unsigned short* gf  = (unsigned short*)(ws + WS_GF);
    float*          xp  = ws + WS_XP;
    float*          xs  = ws + WS_XS;

    k_tables<<<512, 256, 0, stream>>>(egf, tfp);
    k_fs1<<<dim3(8, NH, NB), 256, 0, stream>>>(q, egf, xp);
    k_presum<<<512, 256, 0, stream>>>(xp, xs);
    k_s2<<<256, 256, 0, stream>>>(w1, w2, xs, gf);
    k_s3<<<dim3(64, 4, NB), 256, 0, stream>>>(gf, tfp, out);
}

// Round 9
// 73.065 us; speedup vs baseline: 1.0188x; 1.0188x over previous
//
#include <hip/hip_runtime.h>
#include <hip/hip_bf16.h>
#include <math.h>

// Problem constants
#define NB 8
#define LN 4096       // sequence length L
#define NH 8
#define NE 64
#define NC 512        // NH*NE channels
#define NM 64         // modes kept
#define LMASK 4095

typedef short s16x8 __attribute__((ext_vector_type(8)));
typedef float f32x4 __attribute__((ext_vector_type(4)));

// ws layout (in floats):
//  egf : bf16[128kc][8mt][64][8]        @ 0        (1 MB)  fwd twiddle A-fragments
//  tf  : bf16[4kk][256lt][64][8]        @ 262144   (1 MB)  inv twiddle B-fragments
//  gf  : bf16[8b][4kk][32ct][64][8]     @ 524288   (1 MB)  mixed-spectrum A-fragments
//  xp  : f32[8ks][8b][8h][64i][128m±]   @ 786432   (16 MB) partial fwd GEMM outputs
//  xs  : f32[8b][8h][64i][128m±]        @ 4980736  (2 MB)  ks-summed spectrum
#define WS_EGF 0
#define WS_TF  262144
#define WS_GF  524288
#define WS_XP  786432
#define WS_XS  4980736

static __device__ __forceinline__ unsigned short bf16bits(float f) {
    __hip_bfloat16 b = __float2bfloat16(f);
    return *reinterpret_cast<unsigned short*>(&b);
}

// Both twiddle tables in one launch. Blocks 0..255: egf (fwd A-frags);
// blocks 256..511: tf (inv B-frags).
__global__ __launch_bounds__(256) void k_tables(unsigned short* __restrict__ egf,
                                                unsigned short* __restrict__ tfp) {
    const int bid = blockIdx.x;
    const int s = (bid & 255) * 256 + threadIdx.x;   // 0..65535
    const int lane = s & 63;
    unsigned short v[8];
    if (bid < 256) {
        // E[2m][l]=cos, E[2m+1][l]=-sin ; slot s=(kc<<9)|(mt<<6)|lane
        int mt = (s >> 6) & 7, kc = s >> 9;
        int r = lane & 15, kg = lane >> 4;
        int mpm = mt * 16 + r;
        int m = mpm >> 1, isim = mpm & 1;
        #pragma unroll
        for (int j = 0; j < 8; ++j) {
            int l = kc * 32 + kg * 8 + j;
            int tw = (m * l) & LMASK;
            float ang = (6.283185307179586f / 4096.0f) * (float)tw;
            v[j] = bf16bits(isim ? -sinf(ang) : cosf(ang));
        }
    } else {
        // T[l][2m]=cos, T[l][2m+1]=sin ; slot s=(kk<<14)|(lt<<6)|lane
        int lt = (s >> 6) & 255, kk = s >> 14;
        int l = lt * 16 + (lane & 15);
        int khi = (lane >> 4) * 8;
        #pragma unroll
        for (int j = 0; j < 8; ++j) {
            int mp = kk * 32 + khi + j;
            int m = mp >> 1;
            int tw = (m * l) & LMASK;
            float ang = (6.283185307179586f / 4096.0f) * (float)tw;
            v[j] = bf16bits((mp & 1) ? sinf(ang) : cosf(ang));
        }
    }
    uint4 pk;
    pk.x = (unsigned)v[0] | ((unsigned)v[1] << 16);
    pk.y = (unsigned)v[2] | ((unsigned)v[3] << 16);
    pk.z = (unsigned)v[4] | ((unsigned)v[5] << 16);
    pk.w = (unsigned)v[6] | ((unsigned)v[7] << 16);
    unsigned short* dst = (bid < 256) ? egf : tfp;
    *reinterpret_cast<uint4*>(dst + (size_t)s * 8) = pk;
}

// Fused stage 1 (v5 = measured-best v1 + XOR bank-swizzle on the LDS tile).
// grid (8 ks, 8 h, 8 b) = 512 blocks, block 256 = 4 waves, 2 blocks/CU.
// LDS tile [4 st][32 l][16 i] bf16 = 4 KB, physical row = l ^ ((l>>3)&3)
// (involution; spreads the 4 lane-groups of the B-gather across all banks).
// Per iter (32 l): stage+pack, sync, prefetch, 8 egf A-frags (L2) + swizzled
// B-gather (8 ds_read_u16, conflict-free) + 8 MFMA, sync. 16 iters.
__global__ __launch_bounds__(256, 2) void k_fs1(const float* __restrict__ q,
                                                const unsigned short* __restrict__ egf,
                                                float* __restrict__ xp) {
    __shared__ unsigned short tile[2048];
    const int ks = blockIdx.x, h = blockIdx.y, b = blockIdx.z;
    const int tid = threadIdx.x;
    const int w = tid >> 6, lane = tid & 63;

    // staging: thread loads 8 consecutive i at row sl
    const int sl = tid >> 3;            // 0..31
    const int sc = tid & 7;             // i-chunk (8 i each)
    const float* qbase = q + (((size_t)b * LN + (size_t)ks * 512) * NH + h) * NE + sc * 8;
    uint4* tq4 = reinterpret_cast<uint4*>(tile);
    const int wslot = ((sc >> 1) * 64 + sl * 2 + (sc & 1)) ^ (((sl >> 3) & 3) << 1);

    // B-fragment gather base; per-lane constant row-swizzle delta
    const unsigned short* tp = tile + w * 512 + (lane >> 4) * 128 + (lane & 15);
    const int dlt = (lane >> 4) & 3;

    f32x4 acc[8];
    #pragma unroll
    for (int mt = 0; mt < 8; ++mt) acc[mt] = (f32x4)(0.0f);

#define FS1_LOAD(T, A, B2)                                                        \
    {                                                                             \
        const float* p_ = qbase + ((size_t)(T) * 32 + sl) * NC;                   \
        A  = *reinterpret_cast<const float4*>(p_);                                \
        B2 = *reinterpret_cast<const float4*>(p_ + 4);                            \
    }

    float4 qa, qb_;
    FS1_LOAD(0, qa, qb_)

    for (int t = 0; t < 16; ++t) {
        // pack current rows to bf16, write tile (swizzled slot)
        uint4 pk;
        pk.x = (unsigned)bf16bits(qa.x)  | ((unsigned)bf16bits(qa.y)  << 16);
        pk.y = (unsigned)bf16bits(qa.z)  | ((unsigned)bf16bits(qa.w)  << 16);
        pk.z = (unsigned)bf16bits(qb_.x) | ((unsigned)bf16bits(qb_.y) << 16);
        pk.w = (unsigned)bf16bits(qb_.z) | ((unsigned)bf16bits(qb_.w) << 16);
        tq4[wslot] = pk;
        __syncthreads();

        float4 na, nb;
        if (t < 15) FS1_LOAD(t + 1, na, nb)

        // A fragments (L2-resident, fragment-formatted)
        const unsigned short* ep = egf + (((size_t)(ks * 16 + t) * 8) * 64 + lane) * 8;
        s16x8 af[8];
        #pragma unroll
        for (int mt = 0; mt < 8; ++mt)
            af[mt] = *reinterpret_cast<const s16x8*>(ep + (size_t)mt * 512);

        // B fragment from LDS (k-major gather, row-swizzled -> conflict-free)
        s16x8 bfr;
        #pragma unroll
        for (int j = 0; j < 8; ++j) bfr[j] = (short)tp[(j ^ dlt) * 16];

        #pragma unroll
        for (int mt = 0; mt < 8; ++mt)
            acc[mt] = __builtin_amdgcn_mfma_f32_16x16x32_bf16(af[mt], bfr, acc[mt], 0, 0, 0);
        __syncthreads();

        if (t < 15) { qa = na; qb_ = nb; }
    }
#undef FS1_LOAD

    // Epilogue: D row = m±-local = (lane>>4)*4 + reg, col = i-local = lane&15.
    const int i = w * 16 + (lane & 15);
    float* xpb = xp + ((size_t)ks * 64 + b * 8 + h) * (64 * 128) + (size_t)i * 128 + (lane >> 4) * 4;
    #pragma unroll
    for (int mt = 0; mt < 8; ++mt)
        *reinterpret_cast<f32x4*>(xpb + mt * 16) = acc[mt];
}

// Sum the 8 K-split partials (float4-vectorized; same per-element order).
__global__ __launch_bounds__(256) void k_presum(const float* __restrict__ xp,
                                                float* __restrict__ xs) {
    int e4 = blockIdx.x * 256 + threadIdx.x;     // 0..131071 float4s
    const f32x4* xp4 = reinterpret_cast<const f32x4*>(xp);
    f32x4 s = (f32x4)(0.0f);
    #pragma unroll
    for (int ks = 0; ks < 8; ++ks) s += xp4[(size_t)ks * 131072 + e4];
    reinterpret_cast<f32x4*>(xs)[e4] = s;
}

// Stage 2 (v3, proven): channel mix, gf written directly. grid 256 blocks
// (XCD-swizzled), block 256. sid -> x = sid&7, idx = sid>>3; r = x*8 + (idx&7)
// -> og = r>>3, h = r&7; bb = idx>>3 -> b in {bb*2, bb*2+1}. The 4 bb-partner
// blocks share the same w1/w2 slice on one XCD -> w read once from HBM.
// Block stages xs[2b][h][64i][64m] (64 KB) to LDS, then o-loop runs from LDS.
__global__ __launch_bounds__(256) void k_s2(const float* __restrict__ w1,
                                            const float* __restrict__ w2,
                                            const float* __restrict__ xs,
                                            unsigned short* __restrict__ gf) {
    __shared__ float2 sxs[2][64][64];    // [bsub][i][m] = 64 KB
    const int sid = blockIdx.x;
    const int x   = sid & 7;
    const int idx = sid >> 3;
    const int r   = x * 8 + (idx & 7);   // (og,h) index
    const int og  = r >> 3, h = r & 7;
    const int bb  = idx >> 3;            // 0..3
    const int tt  = threadIdx.x;

    {
        float4* dst = reinterpret_cast<float4*>(&sxs[0][0][0]);
        #pragma unroll
        for (int bs = 0; bs < 2; ++bs) {
            const float4* s4 = reinterpret_cast<const float4*>(
                xs + ((size_t)((bb * 2 + bs) * 8 + h)) * 8192);
            #pragma unroll
            for (int k = 0; k < 8; ++k)
                dst[bs * 2048 + k * 256 + tt] = s4[k * 256 + tt];
        }
    }
    __syncthreads();

    const int m    = tt & 63;
    const int osub = tt >> 6;            // 0..3
    const int o0   = og * 8 + osub * 2;  // 2 o per thread

    float re[2][2], im[2][2];            // [oo][bs]
    #pragma unroll
    for (int oo = 0; oo < 2; ++oo)
        #pragma unroll
        for (int bs = 0; bs < 2; ++bs) { re[oo][bs] = 0.f; im[oo][bs] = 0.f; }

    const float* w1p = w1 + (size_t)h * (NE * NE * NM) + (size_t)o0 * NM + m;
    const float* w2p = w2 + (size_t)h * (NE * NE * NM) + (size_t)o0 * NM + m;

    #pragma unroll 2
    for (int i = 0; i < NE; ++i) {
        float wr0 = w1p[(size_t)i * (NE * NM)];
        float wi0 = w2p[(size_t)i * (NE * NM)];
        float wr1 = w1p[(size_t)i * (NE * NM) + NM];
        float wi1 = w2p[(size_t)i * (NE * NM) + NM];
        #pragma unroll
        for (int bs = 0; bs < 2; ++bs) {
            float2 xv = sxs[bs][i][m];
            re[0][bs] = fmaf(xv.x, wr0, fmaf(-xv.y, wi0, re[0][bs]));
            im[0][bs] = fmaf(xv.x, wi0, fmaf( xv.y, wr0, im[0][bs]));
            re[1][bs] = fmaf(xv.x, wr1, fmaf(-xv.y, wi1, re[1][bs]));
            im[1][bs] = fmaf(xv.x, wi1, fmaf( xv.y, wr1, im[1][bs]));
        }
    }

    const float sca = (m == 0 ? 1.0f : 2.0f) / (float)LN;  // (2-delta_m0)/L fold
    // G[2m][c]=s*re, G[2m+1][c]=-s*im into A-fragment layout:
    // slot = ((b*4 + (m>>4))*32 + (c>>4))*64 + ((m&15)>>2)*16 + (c&15), elems ((m&3)<<1)+{0,1}
    const int kk  = m >> 4;
    const int khi = ((m & 15) >> 2) * 16;
    const int jj  = (m & 3) << 1;
    #pragma unroll
    for (int oo = 0; oo < 2; ++oo) {
        const int c = h * 64 + o0 + oo;
        #pragma unroll
        for (int bs = 0; bs < 2; ++bs) {
            const int b = bb * 2 + bs;
            size_t slot = (((size_t)b * 4 + kk) * 32 + (c >> 4)) * 64 + khi + (c & 15);
            unsigned int pk = (unsigned)bf16bits(re[oo][bs] * sca) |
                              ((unsigned)bf16bits(-im[oo][bs] * sca) << 16);
            *reinterpret_cast<unsigned int*>(gf + slot * 8 + jj) = pk;
        }
    }
}

// Stage 3 MFMA: per b: out[l][c] = sum_mp T[l][mp] * G[mp][c].  M=c(128/block), N=l(64/block), K=128.
// grid (64 lb, 4 cb, 8 b), block 256 = 4 waves; wave w owns c-quarter [w*32, w*32+32).
// Zero LDS / zero barriers; both operand tables stream from L2.
__global__ __launch_bounds__(256, 2) void k_s3(const unsigned short* __restrict__ gf,
                                               const unsigned short* __restrict__ tfp,
                                               float* __restrict__ out) {
    const int lb = blockIdx.x;   // l base = lb*64
    const int cb = blockIdx.y;   // c base = cb*128
    const int b  = blockIdx.z;
    const int tid = threadIdx.x;
    const int w = tid >> 6, lane = tid & 63;

    const unsigned short* ga = gf + ((((size_t)b * 4) * 32 + cb * 8 + w * 2) * 64 + lane) * 8;
    const unsigned short* tb = tfp + (((size_t)lb * 4) * 64 + lane) * 8;

    f32x4 acc[2][4] = {};
    s16x8 af[3][2], bf[3][4];

#define S3_LOAD(T, SLOT)                                                          \
    {                                                                             \
        const unsigned short* gp_ = ga + (size_t)(T) * (32 * 64 * 8);             \
        const unsigned short* tp_ = tb + (size_t)(T) * (256 * 64 * 8);            \
        af[SLOT][0] = *reinterpret_cast<const s16x8*>(gp_);                       \
        af[SLOT][1] = *reinterpret_cast<const s16x8*>(gp_ + 64 * 8);              \
        bf[SLOT][0] = *reinterpret_cast<const s16x8*>(tp_);                       \
        bf[SLOT][1] = *reinterpret_cast<const s16x8*>(tp_ + 64 * 8);              \
        bf[SLOT][2] = *reinterpret_cast<const s16x8*>(tp_ + 2 * 64 * 8);          \
        bf[SLOT][3] = *reinterpret_cast<const s16x8*>(tp_ + 3 * 64 * 8);          \
    }

    S3_LOAD(0, 0)
    S3_LOAD(1, 1)

    #pragma unroll
    for (int t = 0; t < 4; ++t) {
        const int slot = t % 3;
        if (t + 2 < 4) { const int ns = (t + 2) % 3; S3_LOAD(t + 2, ns) }
        #pragma unroll
        for (int mi = 0; mi < 2; ++mi)
            #pragma unroll
            for (int ni = 0; ni < 4; ++ni)
                acc[mi][ni] = __builtin_amdgcn_mfma_f32_16x16x32_bf16(
                    af[slot][mi], bf[slot][ni], acc[mi][ni], 0, 0, 0);
    }
#undef S3_LOAD

    // D[row=c_local][col=l_local]; f32x4 regs span 4 consecutive c.
    const int c0 = cb * 128 + w * 32 + (lane >> 4) * 4;
    const int l0 = lb * 64 + (lane & 15);
    #pragma unroll
    for (int mi = 0; mi < 2; ++mi)
        #pragma unroll
        for (int ni = 0; ni < 4; ++ni) {
            float* op = out + ((size_t)b * LN + l0 + ni * 16) * NC + c0 + mi * 16;
            *reinterpret_cast<f32x4*>(op) = acc[mi][ni];
        }
}

extern "C" void kernel_launch(void* const* d_in, const int* in_sizes, int n_in,
                              void* d_out, int out_size, void* d_ws, size_t ws_size,
                              hipStream_t stream) {
    const float* q  = (const float*)d_in[0];
    // d_in[1] (k) and d_in[2] (v) are unused by the reference
    const float* w1 = (const float*)d_in[3];
    const float* w2 = (const float*)d_in[4];
    float* out = (float*)d_out;
    float* ws  = (float*)d_ws;

    unsigned short* egf = (unsigned short*)(ws + WS_EGF);
    unsigned short* tfp = (unsigned short*)(ws + WS_TF);
    unsigned short* gf  = (unsigned short*)(ws + WS_GF);
    float*          xp  = ws + WS_XP;
    float*          xs  = ws + WS_XS;

    k_tables<<<512, 256, 0, stream>>>(egf, tfp);
    k_fs1<<<dim3(8, NH, NB), 256, 0, stream>>>(q, egf, xp);
    k_presum<<<512, 256, 0, stream>>>(xp, xs);
    k_s2<<<256, 256, 0, stream>>>(w1, w2, xs, gf);
    k_s3<<<dim3(64, 4, NB), 256, 0, stream>>>(gf, tfp, out);
}

// Round 10
// 62.191 us; speedup vs baseline: 1.1970x; 1.1749x over previous
//
#include <hip/hip_runtime.h>
#include <hip/hip_bf16.h>
#include <math.h>

// Problem constants
#define NB 8
#define LN 4096       // sequence length L
#define NH 8
#define NE 64
#define NC 512        // NH*NE channels
#define NM 64         // modes kept
#define LMASK 4095

typedef short s16x8 __attribute__((ext_vector_type(8)));
typedef float f32x4 __attribute__((ext_vector_type(4)));
typedef const __attribute__((address_space(1))) void gv_t;
typedef __attribute__((address_space(3))) void lv_t;

// ws layout (in floats):
//  egf : bf16[128kc][8mt][64][8]        @ 0        (1 MB)  fwd twiddle A-fragments
//  tf  : bf16[4kk][256lt][64][8]        @ 262144   (1 MB)  inv twiddle B-fragments
//  gf  : bf16[8b][4kk][32ct][64][8]     @ 524288   (1 MB)  mixed-spectrum A-fragments
//  xp  : f32[8ks][8b][8h][64i][128m±]   @ 786432   (16 MB) partial fwd GEMM outputs
//  xs  : f32[8b][8h][64i][128m±]        @ 4980736  (2 MB)  ks-summed spectrum
#define WS_EGF 0
#define WS_TF  262144
#define WS_GF  524288
#define WS_XP  786432
#define WS_XS  4980736

static __device__ __forceinline__ unsigned short bf16bits(float f) {
    __hip_bfloat16 b = __float2bfloat16(f);
    return *reinterpret_cast<unsigned short*>(&b);
}

// Both twiddle tables in one launch. Blocks 0..255: egf (fwd A-frags);
// blocks 256..511: tf (inv B-frags).
__global__ __launch_bounds__(256) void k_tables(unsigned short* __restrict__ egf,
                                                unsigned short* __restrict__ tfp) {
    const int bid = blockIdx.x;
    const int s = (bid & 255) * 256 + threadIdx.x;   // 0..65535
    const int lane = s & 63;
    unsigned short v[8];
    if (bid < 256) {
        // E[2m][l]=cos, E[2m+1][l]=-sin ; slot s=(kc<<9)|(mt<<6)|lane
        int mt = (s >> 6) & 7, kc = s >> 9;
        int r = lane & 15, kg = lane >> 4;
        int mpm = mt * 16 + r;
        int m = mpm >> 1, isim = mpm & 1;
        #pragma unroll
        for (int j = 0; j < 8; ++j) {
            int l = kc * 32 + kg * 8 + j;
            int tw = (m * l) & LMASK;
            float ang = (6.283185307179586f / 4096.0f) * (float)tw;
            v[j] = bf16bits(isim ? -sinf(ang) : cosf(ang));
        }
    } else {
        // T[l][2m]=cos, T[l][2m+1]=sin ; slot s=(kk<<14)|(lt<<6)|lane
        int lt = (s >> 6) & 255, kk = s >> 14;
        int l = lt * 16 + (lane & 15);
        int khi = (lane >> 4) * 8;
        #pragma unroll
        for (int j = 0; j < 8; ++j) {
            int mp = kk * 32 + khi + j;
            int m = mp >> 1;
            int tw = (m * l) & LMASK;
            float ang = (6.283185307179586f / 4096.0f) * (float)tw;
            v[j] = bf16bits((mp & 1) ? sinf(ang) : cosf(ang));
        }
    }
    uint4 pk;
    pk.x = (unsigned)v[0] | ((unsigned)v[1] << 16);
    pk.y = (unsigned)v[2] | ((unsigned)v[3] << 16);
    pk.z = (unsigned)v[4] | ((unsigned)v[5] << 16);
    pk.w = (unsigned)v[6] | ((unsigned)v[7] << 16);
    unsigned short* dst = (bid < 256) ? egf : tfp;
    *reinterpret_cast<uint4*>(dst + (size_t)s * 8) = pk;
}

// Fused stage 1 (v6): deep-pipelined global_load_lds staging, counted vmcnt,
// raw s_barrier (no drain). grid (8 ks, 8 h, 8 b) = 512 blocks, 256 thr = 4 waves.
// Per block: 16 tiles x 32 l. LDS: q ring [4][wave][32 l][16 i] f32 (32 KB, each
// wave stages its own i-subtile -> per-lane src, linear dest) + egf ring [4][4096]
// bf16 (32 KB, all 4 waves co-stage, consumed by all). q staged depth-3 (HBM),
// egf depth-2 (L2). vmcnt(8) = keep {q(t+1),q(t+2),e(t+1),e(t+2)} in flight.
// kc order and bf16 rounding identical to v1/v5 -> absmax must stay 2.384186e-07.
__global__ __launch_bounds__(256, 2) void k_fs1(const float* __restrict__ q,
                                                const unsigned short* __restrict__ egf,
                                                float* __restrict__ xp) {
    __shared__ float qlds[4][4][32][16];        // 32 KB: [slot][wave][l][i]
    __shared__ unsigned short eglds[4][4096];   // 32 KB: [slot][frag bytes of one kc]
    const int ks = blockIdx.x, h = blockIdx.y, b = blockIdx.z;
    const int tid = threadIdx.x;
    const int w = tid >> 6, lane = tid & 63;
    const int g = lane >> 4, r = lane & 15;

    // Per-lane global sources (HW writes LDS at uniform base + lane*16).
    // q: lane covers (l_loc = lane>>2, i-quad = lane&3) of wave w's subtile.
    const float* qsrc = q + (((size_t)b * LN + ks * 512 + (lane >> 2)) * NH + h) * NE
                          + w * 16 + (lane & 3) * 4;
    // egf: tile t = one kc = 4096 shorts, contiguous; wave w stages quarter w.
    const unsigned short* esrc = egf + (size_t)(ks * 16) * 4096 + w * 1024 + lane * 8;

#define STAGE_Q(T) { \
    __builtin_amdgcn_global_load_lds((gv_t*)(qsrc + (size_t)(T) * 32 * NC), \
        (lv_t*)(&qlds[(T) & 3][w][0][0]), 16, 0, 0); \
    __builtin_amdgcn_global_load_lds((gv_t*)(qsrc + ((size_t)(T) * 32 + 16) * NC), \
        (lv_t*)(&qlds[(T) & 3][w][16][0]), 16, 0, 0); }

#define STAGE_E(T) { \
    __builtin_amdgcn_global_load_lds((gv_t*)(esrc + (size_t)(T) * 4096), \
        (lv_t*)(&eglds[(T) & 3][w * 1024]), 16, 0, 0); \
    __builtin_amdgcn_global_load_lds((gv_t*)(esrc + (size_t)(T) * 4096 + 512), \
        (lv_t*)(&eglds[(T) & 3][w * 1024 + 512]), 16, 0, 0); }

    f32x4 acc[8];
    #pragma unroll
    for (int mt = 0; mt < 8; ++mt) acc[mt] = (f32x4)(0.0f);

    // Prologue (issue order matters for in-order vmcnt math): q0,e0,e1,q1,q2
    STAGE_Q(0) STAGE_E(0) STAGE_E(1) STAGE_Q(1) STAGE_Q(2)

    #pragma unroll
    for (int t = 0; t < 16; ++t) {
        if (t + 2 < 16) STAGE_E(t + 2)
        // Force q(t) & egf(t) resident; keep {q(t+1),q(t+2),e(t+1),e(t+2)} in flight.
        if (t <= 13)      asm volatile("s_waitcnt vmcnt(8)" ::: "memory");
        else if (t == 14) asm volatile("s_waitcnt vmcnt(4)" ::: "memory");
        else              asm volatile("s_waitcnt vmcnt(0)" ::: "memory");
        __builtin_amdgcn_s_barrier();          // raw barrier: no vmcnt drain
        asm volatile("" ::: "memory");
        if (t + 3 < 16) STAGE_Q(t + 3)

        // A fragments from LDS (lane-contiguous b128 reads)
        s16x8 af[8];
        #pragma unroll
        for (int mt = 0; mt < 8; ++mt)
            af[mt] = *reinterpret_cast<const s16x8*>(&eglds[t & 3][mt * 512 + lane * 8]);
        // B fragment: f32 gather from own subtile, cvt to bf16 (same RNE as before)
        s16x8 bfr;
        #pragma unroll
        for (int j = 0; j < 8; ++j)
            bfr[j] = (short)bf16bits(qlds[t & 3][w][g * 8 + j][r]);

        #pragma unroll
        for (int mt = 0; mt < 8; ++mt)
            acc[mt] = __builtin_amdgcn_mfma_f32_16x16x32_bf16(af[mt], bfr, acc[mt], 0, 0, 0);
    }
#undef STAGE_Q
#undef STAGE_E

    // Epilogue: D row = m±-local = (lane>>4)*4 + reg, col = i-local = lane&15.
    const int i = w * 16 + r;
    float* xpb = xp + ((size_t)ks * 64 + b * 8 + h) * (64 * 128) + (size_t)i * 128 + g * 4;
    #pragma unroll
    for (int mt = 0; mt < 8; ++mt)
        *reinterpret_cast<f32x4*>(xpb + mt * 16) = acc[mt];
}

// Sum the 8 K-split partials (float4-vectorized; same per-element order).
__global__ __launch_bounds__(256) void k_presum(const float* __restrict__ xp,
                                                float* __restrict__ xs) {
    int e4 = blockIdx.x * 256 + threadIdx.x;     // 0..131071 float4s
    const f32x4* xp4 = reinterpret_cast<const f32x4*>(xp);
    f32x4 s = (f32x4)(0.0f);
    #pragma unroll
    for (int ks = 0; ks < 8; ++ks) s += xp4[(size_t)ks * 131072 + e4];
    reinterpret_cast<f32x4*>(xs)[e4] = s;
}

// Stage 2 (v3, proven): channel mix, gf written directly. grid 256 blocks
// (XCD-swizzled), block 256. Block stages xs[2b][h][64i][64m] (64 KB) to LDS,
// then the o-loop runs from LDS; w1/w2 read exactly once across the grid.
__global__ __launch_bounds__(256) void k_s2(const float* __restrict__ w1,
                                            const float* __restrict__ w2,
                                            const float* __restrict__ xs,
                                            unsigned short* __restrict__ gf) {
    __shared__ float2 sxs[2][64][64];    // [bsub][i][m] = 64 KB
    const int sid = blockIdx.x;
    const int x   = sid & 7;
    const int idx = sid >> 3;
    const int r   = x * 8 + (idx & 7);   // (og,h) index
    const int og  = r >> 3, h = r & 7;
    const int bb  = idx >> 3;            // 0..3
    const int tt  = threadIdx.x;

    {
        float4* dst = reinterpret_cast<float4*>(&sxs[0][0][0]);
        #pragma unroll
        for (int bs = 0; bs < 2; ++bs) {
            const float4* s4 = reinterpret_cast<const float4*>(
                xs + ((size_t)((bb * 2 + bs) * 8 + h)) * 8192);
            #pragma unroll
            for (int k = 0; k < 8; ++k)
                dst[bs * 2048 + k * 256 + tt] = s4[k * 256 + tt];
        }
    }
    __syncthreads();

    const int m    = tt & 63;
    const int osub = tt >> 6;            // 0..3
    const int o0   = og * 8 + osub * 2;  // 2 o per thread

    float re[2][2], im[2][2];            // [oo][bs]
    #pragma unroll
    for (int oo = 0; oo < 2; ++oo)
        #pragma unroll
        for (int bs = 0; bs < 2; ++bs) { re[oo][bs] = 0.f; im[oo][bs] = 0.f; }

    const float* w1p = w1 + (size_t)h * (NE * NE * NM) + (size_t)o0 * NM + m;
    const float* w2p = w2 + (size_t)h * (NE * NE * NM) + (size_t)o0 * NM + m;

    #pragma unroll 2
    for (int i = 0; i < NE; ++i) {
        float wr0 = w1p[(size_t)i * (NE * NM)];
        float wi0 = w2p[(size_t)i * (NE * NM)];
        float wr1 = w1p[(size_t)i * (NE * NM) + NM];
        float wi1 = w2p[(size_t)i * (NE * NM) + NM];
        #pragma unroll
        for (int bs = 0; bs < 2; ++bs) {
            float2 xv = sxs[bs][i][m];
            re[0][bs] = fmaf(xv.x, wr0, fmaf(-xv.y, wi0, re[0][bs]));
            im[0][bs] = fmaf(xv.x, wi0, fmaf( xv.y, wr0, im[0][bs]));
            re[1][bs] = fmaf(xv.x, wr1, fmaf(-xv.y, wi1, re[1][bs]));
            im[1][bs] = fmaf(xv.x, wi1, fmaf( xv.y, wr1, im[1][bs]));
        }
    }

    const float sca = (m == 0 ? 1.0f : 2.0f) / (float)LN;  // (2-delta_m0)/L fold
    // G[2m][c]=s*re, G[2m+1][c]=-s*im into A-fragment layout:
    // slot = ((b*4 + (m>>4))*32 + (c>>4))*64 + ((m&15)>>2)*16 + (c&15), elems ((m&3)<<1)+{0,1}
    const int kk  = m >> 4;
    const int khi = ((m & 15) >> 2) * 16;
    const int jj  = (m & 3) << 1;
    #pragma unroll
    for (int oo = 0; oo < 2; ++oo) {
        const int c = h * 64 + o0 + oo;
        #pragma unroll
        for (int bs = 0; bs < 2; ++bs) {
            const int b = bb * 2 + bs;
            size_t slot = (((size_t)b * 4 + kk) * 32 + (c >> 4)) * 64 + khi + (c & 15);
            unsigned int pk = (unsigned)bf16bits(re[oo][bs] * sca) |
                              ((unsigned)bf16bits(-im[oo][bs] * sca) << 16);
            *reinterpret_cast<unsigned int*>(gf + slot * 8 + jj) = pk;
        }
    }
}

// Stage 3 MFMA: per b: out[l][c] = sum_mp T[l][mp] * G[mp][c].  M=c(128/block), N=l(64/block), K=128.
// grid (64 lb, 4 cb, 8 b), block 256 = 4 waves; wave w owns c-quarter [w*32, w*32+32).
// Zero LDS / zero barriers; both operand tables stream from L2.
__global__ __launch_bounds__(256, 2) void k_s3(const unsigned short* __restrict__ gf,
                                               const unsigned short* __restrict__ tfp,
                                               float* __restrict__ out) {
    const int lb = blockIdx.x;   // l base = lb*64
    const int cb = blockIdx.y;   // c base = cb*128
    const int b  = blockIdx.z;
    const int tid = threadIdx.x;
    const int w = tid >> 6, lane = tid & 63;

    const unsigned short* ga = gf + ((((size_t)b * 4) * 32 + cb * 8 + w * 2) * 64 + lane) * 8;
    const unsigned short* tb = tfp + (((size_t)lb * 4) * 64 + lane) * 8;

    f32x4 acc[2][4] = {};
    s16x8 af[3][2], bf[3][4];

#define S3_LOAD(T, SLOT)                                                          \
    {                                                                             \
        const unsigned short* gp_ = ga + (size_t)(T) * (32 * 64 * 8);             \
        const unsigned short* tp_ = tb + (size_t)(T) * (256 * 64 * 8);            \
        af[SLOT][0] = *reinterpret_cast<const s16x8*>(gp_);                       \
        af[SLOT][1] = *reinterpret_cast<const s16x8*>(gp_ + 64 * 8);              \
        bf[SLOT][0] = *reinterpret_cast<const s16x8*>(tp_);                       \
        bf[SLOT][1] = *reinterpret_cast<const s16x8*>(tp_ + 64 * 8);              \
        bf[SLOT][2] = *reinterpret_cast<const s16x8*>(tp_ + 2 * 64 * 8);          \
        bf[SLOT][3] = *reinterpret_cast<const s16x8*>(tp_ + 3 * 64 * 8);          \
    }

    S3_LOAD(0, 0)
    S3_LOAD(1, 1)

    #pragma unroll
    for (int t = 0; t < 4; ++t) {
        const int slot = t % 3;
        if (t + 2 < 4) { const int ns = (t + 2) % 3; S3_LOAD(t + 2, ns) }
        #pragma unroll
        for (int mi = 0; mi < 2; ++mi)
            #pragma unroll
            for (int ni = 0; ni < 4; ++ni)
                acc[mi][ni] = __builtin_amdgcn_mfma_f32_16x16x32_bf16(
                    af[slot][mi], bf[slot][ni], acc[mi][ni], 0, 0, 0);
    }
#undef S3_LOAD

    // D[row=c_local][col=l_local]; f32x4 regs span 4 consecutive c.
    const int c0 = cb * 128 + w * 32 + (lane >> 4) * 4;
    const int l0 = lb * 64 + (lane & 15);
    #pragma unroll
    for (int mi = 0; mi < 2; ++mi)
        #pragma unroll
        for (int ni = 0; ni < 4; ++ni) {
            float* op = out + ((size_t)b * LN + l0 + ni * 16) * NC + c0 + mi * 16;
            *reinterpret_cast<f32x4*>(op) = acc[mi][ni];
        }
}

extern "C" void kernel_launch(void* const* d_in, const int* in_sizes, int n_in,
                              void* d_out, int out_size, void* d_ws, size_t ws_size,
                              hipStream_t stream) {
    const float* q  = (const float*)d_in[0];
    // d_in[1] (k) and d_in[2] (v) are unused by the reference
    const float* w1 = (const float*)d_in[3];
    const float* w2 = (const float*)d_in[4];
    float* out = (float*)d_out;
    float* ws  = (float*)d_ws;

    unsigned short* egf = (unsigned short*)(ws + WS_EGF);
    unsigned short* tfp = (unsigned short*)(ws + WS_TF);
    unsigned short* gf  = (unsigned short*)(ws + WS_GF);
    float*          xp  = ws + WS_XP;
    float*          xs  = ws + WS_XS;

    k_tables<<<512, 256, 0, stream>>>(egf, tfp);
    k_fs1<<<dim3(8, NH, NB), 256, 0, stream>>>(q, egf, xp);
    k_presum<<<512, 256, 0, stream>>>(xp, xs);
    k_s2<<<256, 256, 0, stream>>>(w1, w2, xs, gf);
    k_s3<<<dim3(64, 4, NB), 256, 0, stream>>>(gf, tfp, out);
}